// Round 12
// baseline (566.488 us; speedup 1.0000x reference)
//
#include <hip/hip_runtime.h>
#include <math.h>

// ---- static config ----
// NS=16, NV=4, C=32, RDIM=32, FC_DIM=64, WNUM=416, L=2
#define SQRT3f     1.7320508075688772f
#define INV_SQRT3f 0.5773502691896258f
#define INV_SQRT2f 0.7071067811865476f
#define A0f        0.22360679774997896f   // 1/sqrt(16+4)
#define A1f        0.20412414523193150f   // 1/sqrt(16+8)

typedef __attribute__((ext_vector_type(8))) short bf16x8;
typedef __attribute__((ext_vector_type(4))) float f32x4;

__device__ __forceinline__ float4 ld4(const float* p) {
    return *reinterpret_cast<const float4*>(p);
}

__device__ __forceinline__ unsigned short f2bf(float x) {
    unsigned int u = __float_as_uint(x);
    u = (u + 0x7FFFu + ((u >> 16) & 1u)) >> 16;   // RNE
    return (unsigned short)u;
}
__device__ __forceinline__ float bf2f(unsigned short u) {
    return __uint_as_float(((unsigned int)u) << 16);
}
__device__ __forceinline__ unsigned int pk2(float a, float b) {
    return (unsigned int)f2bf(a) | ((unsigned int)f2bf(b) << 16);
}
__device__ __forceinline__ float bflo(unsigned int u) {
    return __uint_as_float(u << 16);
}
__device__ __forceinline__ float bfhi(unsigned int u) {
    return __uint_as_float(u & 0xFFFF0000u);
}
// r-th bf16 (r=0..3) from a uint2 (4 packed bf16) — r must be compile-time
__device__ __forceinline__ float pick4(uint2 v, int r) {
    return (r == 0) ? bflo(v.x) : (r == 1) ? bfhi(v.x)
         : (r == 2) ? bflo(v.y) : bfhi(v.y);
}

// out[16] = in[16] @ W[16,16] + b ; optional relu (W, b may be LDS)
template<bool RELU>
__device__ __forceinline__ void mm16x16(const float* in, const float* W,
                                        const float* b, float* out)
{
#pragma unroll
    for (int t = 0; t < 16; ++t) out[t] = b[t];
#pragma unroll
    for (int s = 0; s < 16; ++s) {
        float a = in[s];
#pragma unroll
        for (int q = 0; q < 4; ++q) {
            float4 w = *reinterpret_cast<const float4*>(W + s * 16 + q * 4);
            out[q*4+0] += a * w.x; out[q*4+1] += a * w.y;
            out[q*4+2] += a * w.z; out[q*4+3] += a * w.w;
        }
    }
    if (RELU) {
#pragma unroll
        for (int t = 0; t < 16; ++t) out[t] = fmaxf(out[t], 0.f);
    }
}

// blocks [0,nblkA): node embed ; [nblkA,nblkA+nblkB): hist ; rest: weight pack
__global__ __launch_bounds__(256)
void embed_hist_pack_kernel(const float* __restrict__ nf,
                            const float* __restrict__ encW, const float* __restrict__ encb,
                            const float* __restrict__ neW1, const float* __restrict__ neb1,
                            const float* __restrict__ neW2, const float* __restrict__ neb2,
                            float* __restrict__ h0, int N,
                            const int* __restrict__ srcI, int* __restrict__ cntI, int E,
                            const float* __restrict__ fc2W, const float* __restrict__ fc1W,
                            unsigned short* __restrict__ w2p, unsigned short* __restrict__ w1p,
                            int nblkA, int nblkB)
{
    int tid = threadIdx.x;
    int bid = (int)blockIdx.x;
    if (bid >= nblkA + nblkB) {
        // ---- weight pack ----
        int idx = (bid - nblkA - nblkB) * 256 + tid;
        const int NW2 = 2 * 26 * 2 * 64;
        if (idx < NW2) {
            int lane  = idx & 63;
            int ks    = (idx >> 6) & 1;
            int nt    = (idx >> 7) % 26;
            int layer = idx / (26 * 2 * 64);
            const float* W = fc2W + (size_t)layer * 64 * 416;
            unsigned short* out = w2p + (size_t)layer * 26 * 2 * 64 * 8
                                      + (size_t)((nt * 2 + ks) * 64 + lane) * 8;
            int k0 = ks * 32 + (lane >> 4) * 8;
            int c  = nt * 16 + (lane & 15);
#pragma unroll
            for (int j = 0; j < 8; ++j) out[j] = f2bf(W[(size_t)(k0 + j) * 416 + c]);
        } else {
            int i2 = idx - NW2;
            if (i2 >= 2 * 4 * 2 * 64) return;
            int lane  = i2 & 63;
            int ks    = (i2 >> 6) & 1;
            int nt    = (i2 >> 7) & 3;
            int layer = i2 >> 9;
            const float* W = fc1W + (size_t)layer * 48 * 64;
            unsigned short* out = w1p + (size_t)(((layer * 4 + nt) * 2 + ks) * 64 + lane) * 8;
            int k0 = ks * 32 + (lane >> 4) * 8;
            int n  = nt * 16 + (lane & 15);
#pragma unroll
            for (int j = 0; j < 8; ++j) {
                int k = k0 + j;
                out[j] = (k < 48) ? f2bf(W[(size_t)k * 64 + n]) : (unsigned short)0;
            }
        }
        return;
    }
    if (bid >= nblkA) {
        int e = (bid - nblkA) * 256 + tid;
        if (e < E) atomicAdd(&cntI[srcI[e]], 1);
        return;
    }
    __shared__ float encWs[1024];
    __shared__ float neW1s[256];
    __shared__ float neW2s[256];
    __shared__ float bs[48];
    for (int i = tid; i < 1024; i += 256) encWs[i] = encW[i];
    neW1s[tid] = neW1[tid];
    neW2s[tid] = neW2[tid];
    if (tid < 16)      bs[tid] = encb[tid];
    else if (tid < 32) bs[tid] = neb1[tid - 16];
    else if (tid < 48) bs[tid] = neb2[tid - 32];
    __syncthreads();

    int n = bid * 256 + tid;
    if (n >= N) return;
    float x[16];
#pragma unroll
    for (int s = 0; s < 16; ++s) x[s] = bs[s];
    for (int i = 0; i < 64; ++i) {
        float a = nf[(size_t)n * 64 + i];
#pragma unroll
        for (int q = 0; q < 4; ++q) {
            float4 w = *reinterpret_cast<const float4*>(&encWs[i * 16 + q * 4]);
            x[q*4+0] += a * w.x; x[q*4+1] += a * w.y;
            x[q*4+2] += a * w.z; x[q*4+3] += a * w.w;
        }
    }
    float h[16], o[16];
    mm16x16<true >(x, neW1s, bs + 16, h);
    mm16x16<false>(h, neW2s, bs + 32, o);
#pragma unroll
    for (int j = 0; j < 16; ++j) h0[(size_t)n * 16 + j] = o[j];
}

// exclusive scan of cntI -> start/cursor, invcnt; shfl-based
__global__ __launch_bounds__(1024)
void scan_kernel(const int* __restrict__ cntI, int* __restrict__ start,
                 int* __restrict__ cursor, float* __restrict__ invcnt, int N)
{
    __shared__ int wsum[16];
    __shared__ int ctot;
    int tid = threadIdx.x;
    int lane = tid & 63, wid = tid >> 6;
    int run = 0;
    for (int c0 = 0; c0 < N; c0 += 1024) {
        int i = c0 + tid;
        int v = (i < N) ? cntI[i] : 0;
        int x = v;
#pragma unroll
        for (int off = 1; off < 64; off <<= 1) {
            int y = __shfl_up(x, off);
            if (lane >= off) x += y;
        }
        if (lane == 63) wsum[wid] = x;
        __syncthreads();
        if (wid == 0) {
            int w = (lane < 16) ? wsum[lane] : 0;
#pragma unroll
            for (int off = 1; off < 16; off <<= 1) {
                int y = __shfl_up(w, off);
                if (lane >= off) w += y;
            }
            if (lane < 16) wsum[lane] = w;
            if (lane == 15) ctot = w;
        }
        __syncthreads();
        int base = (wid > 0) ? wsum[wid - 1] : 0;
        int incl = x + base;
        if (i < N) {
            int st = run + incl - v;
            start[i] = st;
            cursor[i] = st;
            invcnt[i] = 1.0f / fmaxf((float)v, 1.0f);
        }
        run += ctot;
        __syncthreads();
    }
}

// per-edge: y1, edge_attr; scatter-write to sorted slot via cursor atomic
__global__ __launch_bounds__(256)
void edge_pre_kernel(const float* __restrict__ pos, const float* __restrict__ eain,
                     const int* __restrict__ srcI, const int* __restrict__ dstI,
                     int* __restrict__ cursor,
                     const float* __restrict__ eeW1, const float* __restrict__ eeb1,
                     const float* __restrict__ eeW2, const float* __restrict__ eeb2,
                     const float* __restrict__ reW1, const float* __restrict__ reb1,
                     const float* __restrict__ reW2, const float* __restrict__ reb2,
                     float* __restrict__ eattr, float* __restrict__ y1s,
                     int* __restrict__ srcS, int* __restrict__ dstS, int E)
{
    __shared__ float ws_[1280];   // eeW1(256), eeW2(256), reW1(512), reW2(256)
    __shared__ float bs_[64];
    float* eeW1s = ws_;
    float* eeW2s = ws_ + 256;
    float* reW1s = ws_ + 512;
    float* reW2s = ws_ + 1024;
    int tid = threadIdx.x;
    eeW1s[tid] = eeW1[tid];
    eeW2s[tid] = eeW2[tid];
    reW1s[tid] = reW1[tid];
    reW1s[tid + 256] = reW1[tid + 256];
    reW2s[tid] = reW2[tid];
    if (tid < 16)      bs_[tid] = eeb1[tid];
    else if (tid < 32) bs_[tid] = eeb2[tid - 16];
    else if (tid < 48) bs_[tid] = reb1[tid - 32];
    else if (tid < 64) bs_[tid] = reb2[tid - 48];
    __syncthreads();

    int e = blockIdx.x * blockDim.x + tid;
    if (e >= E) return;
    int s = srcI[e], d = dstI[e];
    int p = atomicAdd(&cursor[s], 1);
    srcS[p] = s; dstS[p] = d;
    float vx = pos[s*3+0] - pos[d*3+0];
    float vy = pos[s*3+1] - pos[d*3+1];
    float vz = pos[s*3+2] - pos[d*3+2];
    float dist = sqrtf(vx*vx + vy*vy + vz*vz);
    float inv = 1.f / fmaxf(dist, 1e-9f);
    y1s[(size_t)p*3+0] = SQRT3f * vx * inv;
    y1s[(size_t)p*3+1] = SQRT3f * vy * inv;
    y1s[(size_t)p*3+2] = SQRT3f * vz * inv;

    const float step  = 12.0f / 31.0f;
    const float coeff = -0.5f / (step * step);
    float rbf[32];
#pragma unroll
    for (int j = 0; j < 32; ++j) {
        float t = dist - (float)j * step;
        rbf[j] = expf(coeff * t * t);
    }

    float ein[16];
#pragma unroll
    for (int j = 0; j < 16; ++j) ein[j] = eain[(size_t)e * 16 + j];

    float t1[16], a1v[16];
    mm16x16<true >(ein, eeW1s, bs_, t1);
    mm16x16<false>(t1, eeW2s, bs_ + 16, a1v);

    float t2[16];
#pragma unroll
    for (int t = 0; t < 16; ++t) t2[t] = bs_[32 + t];
#pragma unroll
    for (int j = 0; j < 32; ++j) {
        float a = rbf[j];
#pragma unroll
        for (int q = 0; q < 4; ++q) {
            float4 w = *reinterpret_cast<const float4*>(&reW1s[j * 16 + q * 4]);
            t2[q*4+0] += a * w.x; t2[q*4+1] += a * w.y;
            t2[q*4+2] += a * w.z; t2[q*4+3] += a * w.w;
        }
    }
#pragma unroll
    for (int t = 0; t < 16; ++t) t2[t] = fmaxf(t2[t], 0.f);
    float a2v[16];
    mm16x16<false>(t2, reW2s, bs_ + 48, a2v);

#pragma unroll
    for (int j = 0; j < 16; ++j) eattr[(size_t)p * 16 + j] = a1v[j] + a2v[j];
}

// ======= fused per-layer kernel =======
// R11 structure; __launch_bounds__(256,3) caps VGPR ~170 (live set ~100) to
// lift occupancy 2->3 waves/SIMD. Spill tripwire: FETCH/WRITE ballooning.
template<bool HAS_L1>
__global__ __launch_bounds__(256, 3)
void fused_tp_kernel(const float* __restrict__ h0, const float* __restrict__ h1,
                     const float* __restrict__ eattr, const float* __restrict__ y1s,
                     const int* __restrict__ srcS, const int* __restrict__ dstS,
                     const unsigned short* __restrict__ w1p, const float* __restrict__ b1,
                     const unsigned short* __restrict__ w2p, const float* __restrict__ b2,
                     float* __restrict__ oo0, float* __restrict__ oo1, int E)
{
    __shared__ unsigned short eas[128 * 64];    // EA, then hid (swizzled chunks)
    __shared__ unsigned short x0sT[16 * 128];   // [feat][edge]
    __shared__ unsigned short x1sT[12 * 128];
    __shared__ unsigned short dotsT[4 * 128];
    __shared__ unsigned short crsT[12 * 128];
    __shared__ unsigned short y1lT[3 * 128];

    int tid = threadIdx.x;
    int ebase = blockIdx.x * 128;

    // ---- phase 0: staging, 2 threads per edge ----
    {
        int lx = tid & 127;
        int half = tid >> 7;
        int p = ebase + lx;
        int sw = lx & 7;
        uint4 pk;
        if (half == 0) {
            float4 va = ld4(eattr + (size_t)p * 16 + 0);
            float4 vb = ld4(eattr + (size_t)p * 16 + 4);
            float4 vc = ld4(eattr + (size_t)p * 16 + 8);
            float4 vd = ld4(eattr + (size_t)p * 16 + 12);
            pk.x = pk2(va.x, va.y); pk.y = pk2(va.z, va.w);
            pk.z = pk2(vb.x, vb.y); pk.w = pk2(vb.z, vb.w);
            *reinterpret_cast<uint4*>(&eas[lx * 64 + ((0 ^ sw) << 3)]) = pk;
            pk.x = pk2(vc.x, vc.y); pk.y = pk2(vc.z, vc.w);
            pk.z = pk2(vd.x, vd.y); pk.w = pk2(vd.z, vd.w);
            *reinterpret_cast<uint4*>(&eas[lx * 64 + ((1 ^ sw) << 3)]) = pk;

            int s = srcS[p];
            va = ld4(h0 + (size_t)s * 16 + 0); vb = ld4(h0 + (size_t)s * 16 + 4);
            vc = ld4(h0 + (size_t)s * 16 + 8); vd = ld4(h0 + (size_t)s * 16 + 12);
            pk.x = pk2(va.x, va.y); pk.y = pk2(va.z, va.w);
            pk.z = pk2(vb.x, vb.y); pk.w = pk2(vb.z, vb.w);
            *reinterpret_cast<uint4*>(&eas[lx * 64 + ((2 ^ sw) << 3)]) = pk;
            pk.x = pk2(vc.x, vc.y); pk.y = pk2(vc.z, vc.w);
            pk.z = pk2(vd.x, vd.y); pk.w = pk2(vd.z, vd.w);
            *reinterpret_cast<uint4*>(&eas[lx * 64 + ((3 ^ sw) << 3)]) = pk;
        } else {
            int d = dstS[p];
            float4 va = ld4(h0 + (size_t)d * 16 + 0);
            float4 vb = ld4(h0 + (size_t)d * 16 + 4);
            float4 vc = ld4(h0 + (size_t)d * 16 + 8);
            float4 vd = ld4(h0 + (size_t)d * 16 + 12);
            pk.x = pk2(va.x, va.y); pk.y = pk2(va.z, va.w);
            pk.z = pk2(vb.x, vb.y); pk.w = pk2(vb.z, vb.w);
            *reinterpret_cast<uint4*>(&eas[lx * 64 + ((4 ^ sw) << 3)]) = pk;
            pk.x = pk2(vc.x, vc.y); pk.y = pk2(vc.z, vc.w);
            pk.z = pk2(vd.x, vd.y); pk.w = pk2(vd.z, vd.w);
            *reinterpret_cast<uint4*>(&eas[lx * 64 + ((5 ^ sw) << 3)]) = pk;
            uint4 z = {0u, 0u, 0u, 0u};
            *reinterpret_cast<uint4*>(&eas[lx * 64 + ((6 ^ sw) << 3)]) = z;
            *reinterpret_cast<uint4*>(&eas[lx * 64 + ((7 ^ sw) << 3)]) = z;

            // x0 transposed [feat][edge]
            x0sT[ 0*128+lx]=f2bf(va.x); x0sT[ 1*128+lx]=f2bf(va.y);
            x0sT[ 2*128+lx]=f2bf(va.z); x0sT[ 3*128+lx]=f2bf(va.w);
            x0sT[ 4*128+lx]=f2bf(vb.x); x0sT[ 5*128+lx]=f2bf(vb.y);
            x0sT[ 6*128+lx]=f2bf(vb.z); x0sT[ 7*128+lx]=f2bf(vb.w);
            x0sT[ 8*128+lx]=f2bf(vc.x); x0sT[ 9*128+lx]=f2bf(vc.y);
            x0sT[10*128+lx]=f2bf(vc.z); x0sT[11*128+lx]=f2bf(vc.w);
            x0sT[12*128+lx]=f2bf(vd.x); x0sT[13*128+lx]=f2bf(vd.y);
            x0sT[14*128+lx]=f2bf(vd.z); x0sT[15*128+lx]=f2bf(vd.w);

            float yv0 = y1s[(size_t)p*3+0], yv1 = y1s[(size_t)p*3+1], yv2 = y1s[(size_t)p*3+2];
            y1lT[0*128+lx] = f2bf(yv0);
            y1lT[1*128+lx] = f2bf(yv1);
            y1lT[2*128+lx] = f2bf(yv2);

            if (HAS_L1) {
#pragma unroll
                for (int v = 0; v < 4; ++v) {
                    float xa = h1[(size_t)d*12 + v*3 + 0];
                    float xb = h1[(size_t)d*12 + v*3 + 1];
                    float xc = h1[(size_t)d*12 + v*3 + 2];
                    x1sT[(v*3+0)*128+lx] = f2bf(xa);
                    x1sT[(v*3+1)*128+lx] = f2bf(xb);
                    x1sT[(v*3+2)*128+lx] = f2bf(xc);
                    dotsT[v*128+lx] = f2bf((xa*yv0 + xb*yv1 + xc*yv2) * INV_SQRT3f);
                    crsT[(v*3+0)*128+lx] = f2bf((xb*yv2 - xc*yv1) * INV_SQRT2f);
                    crsT[(v*3+1)*128+lx] = f2bf((xc*yv0 - xa*yv2) * INV_SQRT2f);
                    crsT[(v*3+2)*128+lx] = f2bf((xa*yv1 - xb*yv0) * INV_SQRT2f);
                }
            }
        }
    }
    __syncthreads();

    int wave = tid >> 6;
    int lane = tid & 63;
    int col = lane & 15;
    int grp = lane >> 4;
    int mrow0 = wave * 32;     // this wave's 32 edges

    // ---- phase A: hid = relu(EA @ W1 + b1) via MFMA ----
    {
        bf16x8 a1[2][2];
#pragma unroll
        for (int m = 0; m < 2; ++m) {
            int row = mrow0 + m * 16 + col;
            int r7 = row & 7;
#pragma unroll
            for (int ks = 0; ks < 2; ++ks) {
                int kc = grp + ks * 4;
                a1[m][ks] = *reinterpret_cast<const bf16x8*>(
                    &eas[row * 64 + ((kc ^ r7) << 3)]);
            }
        }
        f32x4 hacc[4][2];
#pragma unroll
        for (int nt = 0; nt < 4; ++nt) {
            const bf16x8* bp = reinterpret_cast<const bf16x8*>(
                w1p + (size_t)((nt * 2) * 64 + lane) * 8);
            bf16x8 b0 = bp[0];
            bf16x8 b1f = bp[64];
            float bs = b1[nt * 16 + col];
            f32x4 cin = {bs, bs, bs, bs};
#pragma unroll
            for (int m = 0; m < 2; ++m) {
                f32x4 acc = cin;
                acc = __builtin_amdgcn_mfma_f32_16x16x32_bf16(a1[m][0], b0, acc, 0, 0, 0);
                acc = __builtin_amdgcn_mfma_f32_16x16x32_bf16(a1[m][1], b1f, acc, 0, 0, 0);
                hacc[nt][m] = acc;
            }
        }
#pragma unroll
        for (int nt = 0; nt < 4; ++nt) {
            int chunkbase = nt * 2 + (col >> 3);
            int cw = col & 7;
#pragma unroll
            for (int m = 0; m < 2; ++m) {
#pragma unroll
                for (int r = 0; r < 4; ++r) {
                    int edge = mrow0 + m * 16 + grp * 4 + r;
                    unsigned short hv = f2bf(fmaxf(hacc[nt][m][r], 0.f));
                    eas[edge * 64 + ((chunkbase ^ (edge & 7)) << 3) + cw] = hv;
                }
            }
        }
    }

    // A->B dependency is wave-local (wave reads only its own 32 rows)
    asm volatile("s_waitcnt lgkmcnt(0)" ::: "memory");
    __builtin_amdgcn_sched_barrier(0);

    // ---- phase B: P = hid @ W2 + b2, fused TP epilogue ----
    bf16x8 a[2][2];
#pragma unroll
    for (int m = 0; m < 2; ++m) {
        int row = mrow0 + m * 16 + col;
        int r7 = row & 7;
        a[m][0] = *reinterpret_cast<const bf16x8*>(&eas[row * 64 + ((grp ^ r7) << 3)]);
        a[m][1] = *reinterpret_cast<const bf16x8*>(&eas[row * 64 + (((grp + 4) ^ r7) << 3)]);
    }

    float o0a[2][4];
    float t011p[2][4];
    float o1p[2][4][3];
#pragma unroll
    for (int m = 0; m < 2; ++m)
#pragma unroll
        for (int r = 0; r < 4; ++r) {
            o0a[m][r] = 0.f; t011p[m][r] = 0.f;
            o1p[m][r][0] = 0.f; o1p[m][r][1] = 0.f; o1p[m][r][2] = 0.f;
        }

    const int NT = HAS_L1 ? 26 : 20;
    for (int nt = 0; nt < NT; ++nt) {
        const bf16x8* bp = reinterpret_cast<const bf16x8*>(
            w2p + (size_t)(nt * 2 * 64 + lane) * 8);
        bf16x8 b0 = bp[0];
        bf16x8 b1f = bp[64];
        float bias = b2[nt * 16 + col];
        f32x4 cin = {bias, bias, bias, bias};
#pragma unroll
        for (int m = 0; m < 2; ++m) {
            f32x4 acc = cin;
            acc = __builtin_amdgcn_mfma_f32_16x16x32_bf16(a[m][0], b0, acc, 0, 0, 0);
            acc = __builtin_amdgcn_mfma_f32_16x16x32_bf16(a[m][1], b1f, acc, 0, 0, 0);
            int lx0 = mrow0 + m * 16 + grp * 4;
            if (nt < 16) {
                uint2 xv = *reinterpret_cast<const uint2*>(&x0sT[nt * 128 + lx0]);
#pragma unroll
                for (int r = 0; r < 4; ++r)
                    o0a[m][r] += pick4(xv, r) * acc[r];
            } else if (nt < 20) {
                int n = (nt - 16) * 4 + (col >> 2);
                uint2 xv = *reinterpret_cast<const uint2*>(&x0sT[n * 128 + lx0]);
#pragma unroll
                for (int r = 0; r < 4; ++r)
                    t011p[m][r] += pick4(xv, r) * acc[r];
            } else if (nt == 20) {
                int n = col >> 2;
#pragma unroll
                for (int d = 0; d < 3; ++d) {
                    uint2 xv = *reinterpret_cast<const uint2*>(&x1sT[(n * 3 + d) * 128 + lx0]);
#pragma unroll
                    for (int r = 0; r < 4; ++r)
                        o1p[m][r][d] += pick4(xv, r) * acc[r];
                }
            } else if (nt < 25) {
                int n = nt - 21;
                uint2 xv = *reinterpret_cast<const uint2*>(&dotsT[n * 128 + lx0]);
#pragma unroll
                for (int r = 0; r < 4; ++r)
                    o0a[m][r] += pick4(xv, r) * acc[r];
            } else {
                int n = col >> 2;
#pragma unroll
                for (int d = 0; d < 3; ++d) {
                    uint2 xv = *reinterpret_cast<const uint2*>(&crsT[(n * 3 + d) * 128 + lx0]);
#pragma unroll
                    for (int r = 0; r < 4; ++r)
                        o1p[m][r][d] += pick4(xv, r) * acc[r];
                }
            }
        }
    }

    // epilogue: reduce 4-lane partials, add t011*y1, coalesced store
#pragma unroll
    for (int m = 0; m < 2; ++m) {
        int lx0 = mrow0 + m * 16 + grp * 4;
        uint2 yv0 = *reinterpret_cast<const uint2*>(&y1lT[0 * 128 + lx0]);
        uint2 yv1 = *reinterpret_cast<const uint2*>(&y1lT[1 * 128 + lx0]);
        uint2 yv2 = *reinterpret_cast<const uint2*>(&y1lT[2 * 128 + lx0]);
#pragma unroll
        for (int r = 0; r < 4; ++r) {
            int lx = lx0 + r;
            size_t e = (size_t)(ebase + lx);
            float t = t011p[m][r];
            t += __shfl_xor(t, 4);
            t += __shfl_xor(t, 8);
            float yr[3] = {pick4(yv0, r), pick4(yv1, r), pick4(yv2, r)};
            float o1v[3];
#pragma unroll
            for (int d = 0; d < 3; ++d) {
                float v = o1p[m][r][d];
                v += __shfl_xor(v, 4);
                v += __shfl_xor(v, 8);
                o1v[d] = v + t * yr[d];
            }
            oo0[e * 16 + col] = A0f * o0a[m][r];
            if (col < 4) {
#pragma unroll
                for (int d = 0; d < 3; ++d)
                    oo1[e * 12 + col * 3 + d] = A1f * o1v[d];
            }
        }
    }
}

// residual update (float4 segment sums, 8 threads/node); FINAL fuses the
// o3.Linear + sorter epilogue (h stays in LDS, no global h write).
template<bool FINAL>
__global__ __launch_bounds__(256)
void node_update_kernel(float* __restrict__ h0, float* __restrict__ h1,
                        const float* __restrict__ oo0, const float* __restrict__ oo1,
                        const int* __restrict__ start, const int* __restrict__ cntI,
                        const float* __restrict__ invcnt,
                        const float* __restrict__ lin0, const float* __restrict__ lin1,
                        float* __restrict__ out, int N)
{
    __shared__ float lin0s[512];
    __shared__ float lin1s[128];
    __shared__ float hh0[32][16];
    __shared__ float hh1[32][12];

    int tx = threadIdx.x;          // 0..7
    int ty = threadIdx.y;          // 0..31
    int tid = ty * 8 + tx;
    if (FINAL) {
        lin0s[tid] = lin0[tid];
        lin0s[tid + 256] = lin0[tid + 256];
        if (tid < 128) lin1s[tid] = lin1[tid];
    }

    int n = blockIdx.x * 32 + ty;
    if (n < N) {
        int p0 = start[n], c = cntI[n];
        float4 acc = {0.f, 0.f, 0.f, 0.f};
        if (tx < 4) {
            for (int k = 0; k < c; ++k) {
                float4 v = ld4(oo0 + (size_t)(p0 + k) * 16 + tx * 4);
                acc.x += v.x; acc.y += v.y; acc.z += v.z; acc.w += v.w;
            }
        } else if (tx < 7) {
            for (int k = 0; k < c; ++k) {
                float4 v = ld4(oo1 + (size_t)(p0 + k) * 12 + (tx - 4) * 4);
                acc.x += v.x; acc.y += v.y; acc.z += v.z; acc.w += v.w;
            }
        }
        float invc = invcnt[n];
        if (tx < 4) {
            float4 h = ld4(h0 + (size_t)n * 16 + tx * 4);
            h.x += acc.x * invc; h.y += acc.y * invc;
            h.z += acc.z * invc; h.w += acc.w * invc;
            if (FINAL) {
                hh0[ty][tx*4+0] = h.x; hh0[ty][tx*4+1] = h.y;
                hh0[ty][tx*4+2] = h.z; hh0[ty][tx*4+3] = h.w;
            } else {
                *reinterpret_cast<float4*>(h0 + (size_t)n * 16 + tx * 4) = h;
            }
        } else if (tx < 7) {
            float4 h = ld4(h1 + (size_t)n * 12 + (tx - 4) * 4);
            h.x += acc.x * invc; h.y += acc.y * invc;
            h.z += acc.z * invc; h.w += acc.w * invc;
            if (FINAL) {
                hh1[ty][(tx-4)*4+0] = h.x; hh1[ty][(tx-4)*4+1] = h.y;
                hh1[ty][(tx-4)*4+2] = h.z; hh1[ty][(tx-4)*4+3] = h.w;
            } else {
                *reinterpret_cast<float4*>(h1 + (size_t)n * 12 + (tx - 4) * 4) = h;
            }
        }
    }
    if (FINAL) {
        __syncthreads();
        if (n >= N) return;
#pragma unroll
        for (int q = 0; q < 4; ++q) {
            int c = tx * 4 + q;
            float f0 = 0.f;
#pragma unroll
            for (int s = 0; s < 16; ++s) f0 += hh0[ty][s] * lin0s[s * 32 + c];
            float f1x = 0.f, f1y = 0.f, f1z = 0.f;
#pragma unroll
            for (int v = 0; v < 4; ++v) {
                float w = lin1s[v * 32 + c];
                f1x += hh1[ty][v * 3 + 0] * w;
                f1y += hh1[ty][v * 3 + 1] * w;
                f1z += hh1[ty][v * 3 + 2] * w;
            }
            float4 r;
            r.x = f0 * 0.25f;       // 1/sqrt(16)
            r.y = f1x * 0.5f;       // 1/sqrt(4)
            r.z = f1y * 0.5f;
            r.w = f1z * 0.5f;
            *reinterpret_cast<float4*>(out + (size_t)n * 128 + c * 4) = r;
        }
    }
}

extern "C" void kernel_launch(void* const* d_in, const int* in_sizes, int n_in,
                              void* d_out, int out_size, void* d_ws, size_t ws_size,
                              hipStream_t stream)
{
    const float* pos  = (const float*)d_in[0];
    const float* nf   = (const float*)d_in[1];
    const float* eain = (const float*)d_in[2];
    const int*   eidx = (const int*)  d_in[3];
    const float* encW = (const float*)d_in[4];
    const float* encb = (const float*)d_in[5];
    const float* neW1 = (const float*)d_in[6];
    const float* neb1 = (const float*)d_in[7];
    const float* neW2 = (const float*)d_in[8];
    const float* neb2 = (const float*)d_in[9];
    const float* eeW1 = (const float*)d_in[10];
    const float* eeb1 = (const float*)d_in[11];
    const float* eeW2 = (const float*)d_in[12];
    const float* eeb2 = (const float*)d_in[13];
    const float* reW1 = (const float*)d_in[14];
    const float* reb1 = (const float*)d_in[15];
    const float* reW2 = (const float*)d_in[16];
    const float* reb2 = (const float*)d_in[17];
    const float* fc1W = (const float*)d_in[18];
    const float* fc1b = (const float*)d_in[19];
    const float* fc2W = (const float*)d_in[20];
    const float* fc2b = (const float*)d_in[21];
    const float* lin0 = (const float*)d_in[22];
    const float* lin1 = (const float*)d_in[23];

    int N = in_sizes[0] / 3;
    int E = in_sizes[3] / 2;
    const int* srcI = eidx;
    const int* dstI = eidx + E;

    float* ws = (float*)d_ws;
    size_t o = 0;
    float* h0     = ws + o; o += (size_t)N * 16;
    float* h1     = ws + o; o += (size_t)N * 12;
    float* eat    = ws + o; o += (size_t)E * 16;
    float* y1s    = ws + o; o += (size_t)E * 3;
    float* oo0    = ws + o; o += (size_t)E * 16;
    float* oo1    = ws + o; o += (size_t)E * 12;
    float* invcnt = ws + o; o += (size_t)N;
    int* cntI   = (int*)(ws + o); o += (size_t)N;
    int* startA = (int*)(ws + o); o += (size_t)N;
    int* cursor = (int*)(ws + o); o += (size_t)N;
    int* srcS   = (int*)(ws + o); o += (size_t)E;
    int* dstS   = (int*)(ws + o); o += (size_t)E;
    unsigned short* w2p = (unsigned short*)(ws + o); o += 2 * 26 * 2 * 64 * 8 / 2;
    unsigned short* w1p = (unsigned short*)(ws + o); o += 2 * 4 * 2 * 64 * 8 / 2;

    hipMemsetAsync(h1,   0, sizeof(float) * (size_t)N * 12, stream);
    hipMemsetAsync(cntI, 0, sizeof(int) * (size_t)N, stream);

    int nblkA = (N + 255) / 256;
    int nblkB = (E + 255) / 256;
    embed_hist_pack_kernel<<<nblkA + nblkB + 30, 256, 0, stream>>>(
        nf, encW, encb, neW1, neb1, neW2, neb2, h0, N, srcI, cntI, E,
        fc2W, fc1W, w2p, w1p, nblkA, nblkB);

    scan_kernel<<<1, 1024, 0, stream>>>(cntI, startA, cursor, invcnt, N);

    edge_pre_kernel<<<nblkB, 256, 0, stream>>>(
        pos, eain, srcI, dstI, cursor, eeW1, eeb1, eeW2, eeb2,
        reW1, reb1, reW2, reb2, eat, y1s, srcS, dstS, E);

    dim3 nub(8, 32);
    int nublk = (N + 31) / 32;
    for (int i = 0; i < 2; ++i) {
        const float* fb1 = fc1b + (size_t)i * 64;
        const float* fb2 = fc2b + (size_t)i * 416;
        const unsigned short* w1pi = w1p + (size_t)i * 4 * 2 * 64 * 8;
        const unsigned short* w2pi = w2p + (size_t)i * 26 * 2 * 64 * 8;
        if (i == 0) {
            fused_tp_kernel<false><<<E / 128, 256, 0, stream>>>(
                h0, h1, eat, y1s, srcS, dstS, w1pi, fb1, w2pi, fb2, oo0, oo1, E);
            node_update_kernel<false><<<nublk, nub, 0, stream>>>(
                h0, h1, oo0, oo1, startA, cntI, invcnt, lin0, lin1, (float*)d_out, N);
        } else {
            fused_tp_kernel<true><<<E / 128, 256, 0, stream>>>(
                h0, h1, eat, y1s, srcS, dstS, w1pi, fb1, w2pi, fb2, oo0, oo1, E);
            node_update_kernel<true><<<nublk, nub, 0, stream>>>(
                h0, h1, oo0, oo1, startA, cntI, invcnt, lin0, lin1, (float*)d_out, N);
        }
    }
}

// Round 13
// 256.313 us; speedup vs baseline: 2.2101x; 2.2101x over previous
//
#include <hip/hip_runtime.h>
#include <math.h>

// ---- static config ----
// NS=16, NV=4, C=32, RDIM=32, FC_DIM=64, WNUM=416, L=2
#define SQRT3f     1.7320508075688772f
#define INV_SQRT3f 0.5773502691896258f
#define INV_SQRT2f 0.7071067811865476f
#define A0f        0.22360679774997896f   // 1/sqrt(16+4)
#define A1f        0.20412414523193150f   // 1/sqrt(16+8)

typedef __attribute__((ext_vector_type(8))) short bf16x8;
typedef __attribute__((ext_vector_type(4))) float f32x4;

__device__ __forceinline__ float4 ld4(const float* p) {
    return *reinterpret_cast<const float4*>(p);
}

__device__ __forceinline__ unsigned short f2bf(float x) {
    unsigned int u = __float_as_uint(x);
    u = (u + 0x7FFFu + ((u >> 16) & 1u)) >> 16;   // RNE
    return (unsigned short)u;
}
__device__ __forceinline__ float bf2f(unsigned short u) {
    return __uint_as_float(((unsigned int)u) << 16);
}
__device__ __forceinline__ unsigned int pk2(float a, float b) {
    return (unsigned int)f2bf(a) | ((unsigned int)f2bf(b) << 16);
}
__device__ __forceinline__ float bflo(unsigned int u) {
    return __uint_as_float(u << 16);
}
__device__ __forceinline__ float bfhi(unsigned int u) {
    return __uint_as_float(u & 0xFFFF0000u);
}
// r-th bf16 (r=0..3) from a uint2 (4 packed bf16) — r must be compile-time
__device__ __forceinline__ float pick4(uint2 v, int r) {
    return (r == 0) ? bflo(v.x) : (r == 1) ? bfhi(v.x)
         : (r == 2) ? bflo(v.y) : bfhi(v.y);
}

// out[16] = in[16] @ W[16,16] + b ; optional relu (W, b may be LDS)
template<bool RELU>
__device__ __forceinline__ void mm16x16(const float* in, const float* W,
                                        const float* b, float* out)
{
#pragma unroll
    for (int t = 0; t < 16; ++t) out[t] = b[t];
#pragma unroll
    for (int s = 0; s < 16; ++s) {
        float a = in[s];
#pragma unroll
        for (int q = 0; q < 4; ++q) {
            float4 w = *reinterpret_cast<const float4*>(W + s * 16 + q * 4);
            out[q*4+0] += a * w.x; out[q*4+1] += a * w.y;
            out[q*4+2] += a * w.z; out[q*4+3] += a * w.w;
        }
    }
    if (RELU) {
#pragma unroll
        for (int t = 0; t < 16; ++t) out[t] = fmaxf(out[t], 0.f);
    }
}

// blocks [0,nblkA): node embed ; [nblkA,nblkA+nblkB): hist ; rest: weight pack
__global__ __launch_bounds__(256)
void embed_hist_pack_kernel(const float* __restrict__ nf,
                            const float* __restrict__ encW, const float* __restrict__ encb,
                            const float* __restrict__ neW1, const float* __restrict__ neb1,
                            const float* __restrict__ neW2, const float* __restrict__ neb2,
                            float* __restrict__ h0, int N,
                            const int* __restrict__ srcI, int* __restrict__ cntI, int E,
                            const float* __restrict__ fc2W, const float* __restrict__ fc1W,
                            unsigned short* __restrict__ w2p, unsigned short* __restrict__ w1p,
                            int nblkA, int nblkB)
{
    int tid = threadIdx.x;
    int bid = (int)blockIdx.x;
    if (bid >= nblkA + nblkB) {
        // ---- weight pack ----
        int idx = (bid - nblkA - nblkB) * 256 + tid;
        const int NW2 = 2 * 26 * 2 * 64;
        if (idx < NW2) {
            int lane  = idx & 63;
            int ks    = (idx >> 6) & 1;
            int nt    = (idx >> 7) % 26;
            int layer = idx / (26 * 2 * 64);
            const float* W = fc2W + (size_t)layer * 64 * 416;
            unsigned short* out = w2p + (size_t)layer * 26 * 2 * 64 * 8
                                      + (size_t)((nt * 2 + ks) * 64 + lane) * 8;
            int k0 = ks * 32 + (lane >> 4) * 8;
            int c  = nt * 16 + (lane & 15);
#pragma unroll
            for (int j = 0; j < 8; ++j) out[j] = f2bf(W[(size_t)(k0 + j) * 416 + c]);
        } else {
            int i2 = idx - NW2;
            if (i2 >= 2 * 4 * 2 * 64) return;
            int lane  = i2 & 63;
            int ks    = (i2 >> 6) & 1;
            int nt    = (i2 >> 7) & 3;
            int layer = i2 >> 9;
            const float* W = fc1W + (size_t)layer * 48 * 64;
            unsigned short* out = w1p + (size_t)(((layer * 4 + nt) * 2 + ks) * 64 + lane) * 8;
            int k0 = ks * 32 + (lane >> 4) * 8;
            int n  = nt * 16 + (lane & 15);
#pragma unroll
            for (int j = 0; j < 8; ++j) {
                int k = k0 + j;
                out[j] = (k < 48) ? f2bf(W[(size_t)k * 64 + n]) : (unsigned short)0;
            }
        }
        return;
    }
    if (bid >= nblkA) {
        int e = (bid - nblkA) * 256 + tid;
        if (e < E) atomicAdd(&cntI[srcI[e]], 1);
        return;
    }
    __shared__ float encWs[1024];
    __shared__ float neW1s[256];
    __shared__ float neW2s[256];
    __shared__ float bs[48];
    for (int i = tid; i < 1024; i += 256) encWs[i] = encW[i];
    neW1s[tid] = neW1[tid];
    neW2s[tid] = neW2[tid];
    if (tid < 16)      bs[tid] = encb[tid];
    else if (tid < 32) bs[tid] = neb1[tid - 16];
    else if (tid < 48) bs[tid] = neb2[tid - 32];
    __syncthreads();

    int n = bid * 256 + tid;
    if (n >= N) return;
    float x[16];
#pragma unroll
    for (int s = 0; s < 16; ++s) x[s] = bs[s];
    for (int i = 0; i < 64; ++i) {
        float a = nf[(size_t)n * 64 + i];
#pragma unroll
        for (int q = 0; q < 4; ++q) {
            float4 w = *reinterpret_cast<const float4*>(&encWs[i * 16 + q * 4]);
            x[q*4+0] += a * w.x; x[q*4+1] += a * w.y;
            x[q*4+2] += a * w.z; x[q*4+3] += a * w.w;
        }
    }
    float h[16], o[16];
    mm16x16<true >(x, neW1s, bs + 16, h);
    mm16x16<false>(h, neW2s, bs + 32, o);
#pragma unroll
    for (int j = 0; j < 16; ++j) h0[(size_t)n * 16 + j] = o[j];
}

// exclusive scan of cntI -> start/cursor, invcnt; shfl-based
__global__ __launch_bounds__(1024)
void scan_kernel(const int* __restrict__ cntI, int* __restrict__ start,
                 int* __restrict__ cursor, float* __restrict__ invcnt, int N)
{
    __shared__ int wsum[16];
    __shared__ int ctot;
    int tid = threadIdx.x;
    int lane = tid & 63, wid = tid >> 6;
    int run = 0;
    for (int c0 = 0; c0 < N; c0 += 1024) {
        int i = c0 + tid;
        int v = (i < N) ? cntI[i] : 0;
        int x = v;
#pragma unroll
        for (int off = 1; off < 64; off <<= 1) {
            int y = __shfl_up(x, off);
            if (lane >= off) x += y;
        }
        if (lane == 63) wsum[wid] = x;
        __syncthreads();
        if (wid == 0) {
            int w = (lane < 16) ? wsum[lane] : 0;
#pragma unroll
            for (int off = 1; off < 16; off <<= 1) {
                int y = __shfl_up(w, off);
                if (lane >= off) w += y;
            }
            if (lane < 16) wsum[lane] = w;
            if (lane == 15) ctot = w;
        }
        __syncthreads();
        int base = (wid > 0) ? wsum[wid - 1] : 0;
        int incl = x + base;
        if (i < N) {
            int st = run + incl - v;
            start[i] = st;
            cursor[i] = st;
            invcnt[i] = 1.0f / fmaxf((float)v, 1.0f);
        }
        run += ctot;
        __syncthreads();
    }
}

// per-edge: y1, edge_attr; scatter-write to sorted slot via cursor atomic
__global__ __launch_bounds__(256)
void edge_pre_kernel(const float* __restrict__ pos, const float* __restrict__ eain,
                     const int* __restrict__ srcI, const int* __restrict__ dstI,
                     int* __restrict__ cursor,
                     const float* __restrict__ eeW1, const float* __restrict__ eeb1,
                     const float* __restrict__ eeW2, const float* __restrict__ eeb2,
                     const float* __restrict__ reW1, const float* __restrict__ reb1,
                     const float* __restrict__ reW2, const float* __restrict__ reb2,
                     float* __restrict__ eattr, float* __restrict__ y1s,
                     int* __restrict__ srcS, int* __restrict__ dstS, int E)
{
    __shared__ float ws_[1280];   // eeW1(256), eeW2(256), reW1(512), reW2(256)
    __shared__ float bs_[64];
    float* eeW1s = ws_;
    float* eeW2s = ws_ + 256;
    float* reW1s = ws_ + 512;
    float* reW2s = ws_ + 1024;
    int tid = threadIdx.x;
    eeW1s[tid] = eeW1[tid];
    eeW2s[tid] = eeW2[tid];
    reW1s[tid] = reW1[tid];
    reW1s[tid + 256] = reW1[tid + 256];
    reW2s[tid] = reW2[tid];
    if (tid < 16)      bs_[tid] = eeb1[tid];
    else if (tid < 32) bs_[tid] = eeb2[tid - 16];
    else if (tid < 48) bs_[tid] = reb1[tid - 32];
    else if (tid < 64) bs_[tid] = reb2[tid - 48];
    __syncthreads();

    int e = blockIdx.x * blockDim.x + tid;
    if (e >= E) return;
    int s = srcI[e], d = dstI[e];
    int p = atomicAdd(&cursor[s], 1);
    srcS[p] = s; dstS[p] = d;
    float vx = pos[s*3+0] - pos[d*3+0];
    float vy = pos[s*3+1] - pos[d*3+1];
    float vz = pos[s*3+2] - pos[d*3+2];
    float dist = sqrtf(vx*vx + vy*vy + vz*vz);
    float inv = 1.f / fmaxf(dist, 1e-9f);
    y1s[(size_t)p*3+0] = SQRT3f * vx * inv;
    y1s[(size_t)p*3+1] = SQRT3f * vy * inv;
    y1s[(size_t)p*3+2] = SQRT3f * vz * inv;

    const float step  = 12.0f / 31.0f;
    const float coeff = -0.5f / (step * step);
    float rbf[32];
#pragma unroll
    for (int j = 0; j < 32; ++j) {
        float t = dist - (float)j * step;
        rbf[j] = expf(coeff * t * t);
    }

    float ein[16];
#pragma unroll
    for (int j = 0; j < 16; ++j) ein[j] = eain[(size_t)e * 16 + j];

    float t1[16], a1v[16];
    mm16x16<true >(ein, eeW1s, bs_, t1);
    mm16x16<false>(t1, eeW2s, bs_ + 16, a1v);

    float t2[16];
#pragma unroll
    for (int t = 0; t < 16; ++t) t2[t] = bs_[32 + t];
#pragma unroll
    for (int j = 0; j < 32; ++j) {
        float a = rbf[j];
#pragma unroll
        for (int q = 0; q < 4; ++q) {
            float4 w = *reinterpret_cast<const float4*>(&reW1s[j * 16 + q * 4]);
            t2[q*4+0] += a * w.x; t2[q*4+1] += a * w.y;
            t2[q*4+2] += a * w.z; t2[q*4+3] += a * w.w;
        }
    }
#pragma unroll
    for (int t = 0; t < 16; ++t) t2[t] = fmaxf(t2[t], 0.f);
    float a2v[16];
    mm16x16<false>(t2, reW2s, bs_ + 48, a2v);

#pragma unroll
    for (int j = 0; j < 16; ++j) eattr[(size_t)p * 16 + j] = a1v[j] + a2v[j];
}

// ======= fused per-layer kernel =======
// R11 proven config: plain __launch_bounds__(256) — 192 VGPR, no spill.
// (R6/R12 lesson: any 2nd launch_bounds arg spills phase-B accumulators:
//  (256,2)->128 VGPR/616MB, (256,3)->84 VGPR/838MB. DO NOT CAP.)
template<bool HAS_L1>
__global__ __launch_bounds__(256)
void fused_tp_kernel(const float* __restrict__ h0, const float* __restrict__ h1,
                     const float* __restrict__ eattr, const float* __restrict__ y1s,
                     const int* __restrict__ srcS, const int* __restrict__ dstS,
                     const unsigned short* __restrict__ w1p, const float* __restrict__ b1,
                     const unsigned short* __restrict__ w2p, const float* __restrict__ b2,
                     float* __restrict__ oo0, float* __restrict__ oo1, int E)
{
    __shared__ unsigned short eas[128 * 64];    // EA, then hid (swizzled chunks)
    __shared__ unsigned short x0sT[16 * 128];   // [feat][edge]
    __shared__ unsigned short x1sT[12 * 128];
    __shared__ unsigned short dotsT[4 * 128];
    __shared__ unsigned short crsT[12 * 128];
    __shared__ unsigned short y1lT[3 * 128];

    int tid = threadIdx.x;
    int ebase = blockIdx.x * 128;

    // ---- phase 0: staging, 2 threads per edge ----
    {
        int lx = tid & 127;
        int half = tid >> 7;
        int p = ebase + lx;
        int sw = lx & 7;
        uint4 pk;
        if (half == 0) {
            float4 va = ld4(eattr + (size_t)p * 16 + 0);
            float4 vb = ld4(eattr + (size_t)p * 16 + 4);
            float4 vc = ld4(eattr + (size_t)p * 16 + 8);
            float4 vd = ld4(eattr + (size_t)p * 16 + 12);
            pk.x = pk2(va.x, va.y); pk.y = pk2(va.z, va.w);
            pk.z = pk2(vb.x, vb.y); pk.w = pk2(vb.z, vb.w);
            *reinterpret_cast<uint4*>(&eas[lx * 64 + ((0 ^ sw) << 3)]) = pk;
            pk.x = pk2(vc.x, vc.y); pk.y = pk2(vc.z, vc.w);
            pk.z = pk2(vd.x, vd.y); pk.w = pk2(vd.z, vd.w);
            *reinterpret_cast<uint4*>(&eas[lx * 64 + ((1 ^ sw) << 3)]) = pk;

            int s = srcS[p];
            va = ld4(h0 + (size_t)s * 16 + 0); vb = ld4(h0 + (size_t)s * 16 + 4);
            vc = ld4(h0 + (size_t)s * 16 + 8); vd = ld4(h0 + (size_t)s * 16 + 12);
            pk.x = pk2(va.x, va.y); pk.y = pk2(va.z, va.w);
            pk.z = pk2(vb.x, vb.y); pk.w = pk2(vb.z, vb.w);
            *reinterpret_cast<uint4*>(&eas[lx * 64 + ((2 ^ sw) << 3)]) = pk;
            pk.x = pk2(vc.x, vc.y); pk.y = pk2(vc.z, vc.w);
            pk.z = pk2(vd.x, vd.y); pk.w = pk2(vd.z, vd.w);
            *reinterpret_cast<uint4*>(&eas[lx * 64 + ((3 ^ sw) << 3)]) = pk;
        } else {
            int d = dstS[p];
            float4 va = ld4(h0 + (size_t)d * 16 + 0);
            float4 vb = ld4(h0 + (size_t)d * 16 + 4);
            float4 vc = ld4(h0 + (size_t)d * 16 + 8);
            float4 vd = ld4(h0 + (size_t)d * 16 + 12);
            pk.x = pk2(va.x, va.y); pk.y = pk2(va.z, va.w);
            pk.z = pk2(vb.x, vb.y); pk.w = pk2(vb.z, vb.w);
            *reinterpret_cast<uint4*>(&eas[lx * 64 + ((4 ^ sw) << 3)]) = pk;
            pk.x = pk2(vc.x, vc.y); pk.y = pk2(vc.z, vc.w);
            pk.z = pk2(vd.x, vd.y); pk.w = pk2(vd.z, vd.w);
            *reinterpret_cast<uint4*>(&eas[lx * 64 + ((5 ^ sw) << 3)]) = pk;
            uint4 z = {0u, 0u, 0u, 0u};
            *reinterpret_cast<uint4*>(&eas[lx * 64 + ((6 ^ sw) << 3)]) = z;
            *reinterpret_cast<uint4*>(&eas[lx * 64 + ((7 ^ sw) << 3)]) = z;

            // x0 transposed [feat][edge]
            x0sT[ 0*128+lx]=f2bf(va.x); x0sT[ 1*128+lx]=f2bf(va.y);
            x0sT[ 2*128+lx]=f2bf(va.z); x0sT[ 3*128+lx]=f2bf(va.w);
            x0sT[ 4*128+lx]=f2bf(vb.x); x0sT[ 5*128+lx]=f2bf(vb.y);
            x0sT[ 6*128+lx]=f2bf(vb.z); x0sT[ 7*128+lx]=f2bf(vb.w);
            x0sT[ 8*128+lx]=f2bf(vc.x); x0sT[ 9*128+lx]=f2bf(vc.y);
            x0sT[10*128+lx]=f2bf(vc.z); x0sT[11*128+lx]=f2bf(vc.w);
            x0sT[12*128+lx]=f2bf(vd.x); x0sT[13*128+lx]=f2bf(vd.y);
            x0sT[14*128+lx]=f2bf(vd.z); x0sT[15*128+lx]=f2bf(vd.w);

            float yv0 = y1s[(size_t)p*3+0], yv1 = y1s[(size_t)p*3+1], yv2 = y1s[(size_t)p*3+2];
            y1lT[0*128+lx] = f2bf(yv0);
            y1lT[1*128+lx] = f2bf(yv1);
            y1lT[2*128+lx] = f2bf(yv2);

            if (HAS_L1) {
#pragma unroll
                for (int v = 0; v < 4; ++v) {
                    float xa = h1[(size_t)d*12 + v*3 + 0];
                    float xb = h1[(size_t)d*12 + v*3 + 1];
                    float xc = h1[(size_t)d*12 + v*3 + 2];
                    x1sT[(v*3+0)*128+lx] = f2bf(xa);
                    x1sT[(v*3+1)*128+lx] = f2bf(xb);
                    x1sT[(v*3+2)*128+lx] = f2bf(xc);
                    dotsT[v*128+lx] = f2bf((xa*yv0 + xb*yv1 + xc*yv2) * INV_SQRT3f);
                    crsT[(v*3+0)*128+lx] = f2bf((xb*yv2 - xc*yv1) * INV_SQRT2f);
                    crsT[(v*3+1)*128+lx] = f2bf((xc*yv0 - xa*yv2) * INV_SQRT2f);
                    crsT[(v*3+2)*128+lx] = f2bf((xa*yv1 - xb*yv0) * INV_SQRT2f);
                }
            }
        }
    }
    __syncthreads();

    int wave = tid >> 6;
    int lane = tid & 63;
    int col = lane & 15;
    int grp = lane >> 4;
    int mrow0 = wave * 32;     // this wave's 32 edges

    // ---- phase A: hid = relu(EA @ W1 + b1) via MFMA ----
    {
        bf16x8 a1[2][2];
#pragma unroll
        for (int m = 0; m < 2; ++m) {
            int row = mrow0 + m * 16 + col;
            int r7 = row & 7;
#pragma unroll
            for (int ks = 0; ks < 2; ++ks) {
                int kc = grp + ks * 4;
                a1[m][ks] = *reinterpret_cast<const bf16x8*>(
                    &eas[row * 64 + ((kc ^ r7) << 3)]);
            }
        }
        f32x4 hacc[4][2];
#pragma unroll
        for (int nt = 0; nt < 4; ++nt) {
            const bf16x8* bp = reinterpret_cast<const bf16x8*>(
                w1p + (size_t)((nt * 2) * 64 + lane) * 8);
            bf16x8 b0 = bp[0];
            bf16x8 b1f = bp[64];
            float bs = b1[nt * 16 + col];
            f32x4 cin = {bs, bs, bs, bs};
#pragma unroll
            for (int m = 0; m < 2; ++m) {
                f32x4 acc = cin;
                acc = __builtin_amdgcn_mfma_f32_16x16x32_bf16(a1[m][0], b0, acc, 0, 0, 0);
                acc = __builtin_amdgcn_mfma_f32_16x16x32_bf16(a1[m][1], b1f, acc, 0, 0, 0);
                hacc[nt][m] = acc;
            }
        }
#pragma unroll
        for (int nt = 0; nt < 4; ++nt) {
            int chunkbase = nt * 2 + (col >> 3);
            int cw = col & 7;
#pragma unroll
            for (int m = 0; m < 2; ++m) {
#pragma unroll
                for (int r = 0; r < 4; ++r) {
                    int edge = mrow0 + m * 16 + grp * 4 + r;
                    unsigned short hv = f2bf(fmaxf(hacc[nt][m][r], 0.f));
                    eas[edge * 64 + ((chunkbase ^ (edge & 7)) << 3) + cw] = hv;
                }
            }
        }
    }

    // A->B dependency is wave-local (wave reads only its own 32 rows)
    asm volatile("s_waitcnt lgkmcnt(0)" ::: "memory");
    __builtin_amdgcn_sched_barrier(0);

    // ---- phase B: P = hid @ W2 + b2, fused TP epilogue ----
    bf16x8 a[2][2];
#pragma unroll
    for (int m = 0; m < 2; ++m) {
        int row = mrow0 + m * 16 + col;
        int r7 = row & 7;
        a[m][0] = *reinterpret_cast<const bf16x8*>(&eas[row * 64 + ((grp ^ r7) << 3)]);
        a[m][1] = *reinterpret_cast<const bf16x8*>(&eas[row * 64 + (((grp + 4) ^ r7) << 3)]);
    }

    float o0a[2][4];
    float t011p[2][4];
    float o1p[2][4][3];
#pragma unroll
    for (int m = 0; m < 2; ++m)
#pragma unroll
        for (int r = 0; r < 4; ++r) {
            o0a[m][r] = 0.f; t011p[m][r] = 0.f;
            o1p[m][r][0] = 0.f; o1p[m][r][1] = 0.f; o1p[m][r][2] = 0.f;
        }

    const int NT = HAS_L1 ? 26 : 20;
    for (int nt = 0; nt < NT; ++nt) {
        const bf16x8* bp = reinterpret_cast<const bf16x8*>(
            w2p + (size_t)(nt * 2 * 64 + lane) * 8);
        bf16x8 b0 = bp[0];
        bf16x8 b1f = bp[64];
        float bias = b2[nt * 16 + col];
        f32x4 cin = {bias, bias, bias, bias};
#pragma unroll
        for (int m = 0; m < 2; ++m) {
            f32x4 acc = cin;
            acc = __builtin_amdgcn_mfma_f32_16x16x32_bf16(a[m][0], b0, acc, 0, 0, 0);
            acc = __builtin_amdgcn_mfma_f32_16x16x32_bf16(a[m][1], b1f, acc, 0, 0, 0);
            int lx0 = mrow0 + m * 16 + grp * 4;
            if (nt < 16) {
                uint2 xv = *reinterpret_cast<const uint2*>(&x0sT[nt * 128 + lx0]);
#pragma unroll
                for (int r = 0; r < 4; ++r)
                    o0a[m][r] += pick4(xv, r) * acc[r];
            } else if (nt < 20) {
                int n = (nt - 16) * 4 + (col >> 2);
                uint2 xv = *reinterpret_cast<const uint2*>(&x0sT[n * 128 + lx0]);
#pragma unroll
                for (int r = 0; r < 4; ++r)
                    t011p[m][r] += pick4(xv, r) * acc[r];
            } else if (nt == 20) {
                int n = col >> 2;
#pragma unroll
                for (int d = 0; d < 3; ++d) {
                    uint2 xv = *reinterpret_cast<const uint2*>(&x1sT[(n * 3 + d) * 128 + lx0]);
#pragma unroll
                    for (int r = 0; r < 4; ++r)
                        o1p[m][r][d] += pick4(xv, r) * acc[r];
                }
            } else if (nt < 25) {
                int n = nt - 21;
                uint2 xv = *reinterpret_cast<const uint2*>(&dotsT[n * 128 + lx0]);
#pragma unroll
                for (int r = 0; r < 4; ++r)
                    o0a[m][r] += pick4(xv, r) * acc[r];
            } else {
                int n = col >> 2;
#pragma unroll
                for (int d = 0; d < 3; ++d) {
                    uint2 xv = *reinterpret_cast<const uint2*>(&crsT[(n * 3 + d) * 128 + lx0]);
#pragma unroll
                    for (int r = 0; r < 4; ++r)
                        o1p[m][r][d] += pick4(xv, r) * acc[r];
                }
            }
        }
    }

    // epilogue: reduce 4-lane partials, add t011*y1, coalesced store
#pragma unroll
    for (int m = 0; m < 2; ++m) {
        int lx0 = mrow0 + m * 16 + grp * 4;
        uint2 yv0 = *reinterpret_cast<const uint2*>(&y1lT[0 * 128 + lx0]);
        uint2 yv1 = *reinterpret_cast<const uint2*>(&y1lT[1 * 128 + lx0]);
        uint2 yv2 = *reinterpret_cast<const uint2*>(&y1lT[2 * 128 + lx0]);
#pragma unroll
        for (int r = 0; r < 4; ++r) {
            int lx = lx0 + r;
            size_t e = (size_t)(ebase + lx);
            float t = t011p[m][r];
            t += __shfl_xor(t, 4);
            t += __shfl_xor(t, 8);
            float yr[3] = {pick4(yv0, r), pick4(yv1, r), pick4(yv2, r)};
            float o1v[3];
#pragma unroll
            for (int d = 0; d < 3; ++d) {
                float v = o1p[m][r][d];
                v += __shfl_xor(v, 4);
                v += __shfl_xor(v, 8);
                o1v[d] = v + t * yr[d];
            }
            oo0[e * 16 + col] = A0f * o0a[m][r];
            if (col < 4) {
#pragma unroll
                for (int d = 0; d < 3; ++d)
                    oo1[e * 12 + col * 3 + d] = A1f * o1v[d];
            }
        }
    }
}

// residual update (float4 segment sums, 8 threads/node); FINAL fuses the
// o3.Linear + sorter epilogue (h stays in LDS, no global h write).
template<bool FINAL>
__global__ __launch_bounds__(256)
void node_update_kernel(float* __restrict__ h0, float* __restrict__ h1,
                        const float* __restrict__ oo0, const float* __restrict__ oo1,
                        const int* __restrict__ start, const int* __restrict__ cntI,
                        const float* __restrict__ invcnt,
                        const float* __restrict__ lin0, const float* __restrict__ lin1,
                        float* __restrict__ out, int N)
{
    __shared__ float lin0s[512];
    __shared__ float lin1s[128];
    __shared__ float hh0[32][16];
    __shared__ float hh1[32][12];

    int tx = threadIdx.x;          // 0..7
    int ty = threadIdx.y;          // 0..31
    int tid = ty * 8 + tx;
    if (FINAL) {
        lin0s[tid] = lin0[tid];
        lin0s[tid + 256] = lin0[tid + 256];
        if (tid < 128) lin1s[tid] = lin1[tid];
    }

    int n = blockIdx.x * 32 + ty;
    if (n < N) {
        int p0 = start[n], c = cntI[n];
        float4 acc = {0.f, 0.f, 0.f, 0.f};
        if (tx < 4) {
            for (int k = 0; k < c; ++k) {
                float4 v = ld4(oo0 + (size_t)(p0 + k) * 16 + tx * 4);
                acc.x += v.x; acc.y += v.y; acc.z += v.z; acc.w += v.w;
            }
        } else if (tx < 7) {
            for (int k = 0; k < c; ++k) {
                float4 v = ld4(oo1 + (size_t)(p0 + k) * 12 + (tx - 4) * 4);
                acc.x += v.x; acc.y += v.y; acc.z += v.z; acc.w += v.w;
            }
        }
        float invc = invcnt[n];
        if (tx < 4) {
            float4 h = ld4(h0 + (size_t)n * 16 + tx * 4);
            h.x += acc.x * invc; h.y += acc.y * invc;
            h.z += acc.z * invc; h.w += acc.w * invc;
            if (FINAL) {
                hh0[ty][tx*4+0] = h.x; hh0[ty][tx*4+1] = h.y;
                hh0[ty][tx*4+2] = h.z; hh0[ty][tx*4+3] = h.w;
            } else {
                *reinterpret_cast<float4*>(h0 + (size_t)n * 16 + tx * 4) = h;
            }
        } else if (tx < 7) {
            float4 h = ld4(h1 + (size_t)n * 12 + (tx - 4) * 4);
            h.x += acc.x * invc; h.y += acc.y * invc;
            h.z += acc.z * invc; h.w += acc.w * invc;
            if (FINAL) {
                hh1[ty][(tx-4)*4+0] = h.x; hh1[ty][(tx-4)*4+1] = h.y;
                hh1[ty][(tx-4)*4+2] = h.z; hh1[ty][(tx-4)*4+3] = h.w;
            } else {
                *reinterpret_cast<float4*>(h1 + (size_t)n * 12 + (tx - 4) * 4) = h;
            }
        }
    }
    if (FINAL) {
        __syncthreads();
        if (n >= N) return;
#pragma unroll
        for (int q = 0; q < 4; ++q) {
            int c = tx * 4 + q;
            float f0 = 0.f;
#pragma unroll
            for (int s = 0; s < 16; ++s) f0 += hh0[ty][s] * lin0s[s * 32 + c];
            float f1x = 0.f, f1y = 0.f, f1z = 0.f;
#pragma unroll
            for (int v = 0; v < 4; ++v) {
                float w = lin1s[v * 32 + c];
                f1x += hh1[ty][v * 3 + 0] * w;
                f1y += hh1[ty][v * 3 + 1] * w;
                f1z += hh1[ty][v * 3 + 2] * w;
            }
            float4 r;
            r.x = f0 * 0.25f;       // 1/sqrt(16)
            r.y = f1x * 0.5f;       // 1/sqrt(4)
            r.z = f1y * 0.5f;
            r.w = f1z * 0.5f;
            *reinterpret_cast<float4*>(out + (size_t)n * 128 + c * 4) = r;
        }
    }
}

extern "C" void kernel_launch(void* const* d_in, const int* in_sizes, int n_in,
                              void* d_out, int out_size, void* d_ws, size_t ws_size,
                              hipStream_t stream)
{
    const float* pos  = (const float*)d_in[0];
    const float* nf   = (const float*)d_in[1];
    const float* eain = (const float*)d_in[2];
    const int*   eidx = (const int*)  d_in[3];
    const float* encW = (const float*)d_in[4];
    const float* encb = (const float*)d_in[5];
    const float* neW1 = (const float*)d_in[6];
    const float* neb1 = (const float*)d_in[7];
    const float* neW2 = (const float*)d_in[8];
    const float* neb2 = (const float*)d_in[9];
    const float* eeW1 = (const float*)d_in[10];
    const float* eeb1 = (const float*)d_in[11];
    const float* eeW2 = (const float*)d_in[12];
    const float* eeb2 = (const float*)d_in[13];
    const float* reW1 = (const float*)d_in[14];
    const float* reb1 = (const float*)d_in[15];
    const float* reW2 = (const float*)d_in[16];
    const float* reb2 = (const float*)d_in[17];
    const float* fc1W = (const float*)d_in[18];
    const float* fc1b = (const float*)d_in[19];
    const float* fc2W = (const float*)d_in[20];
    const float* fc2b = (const float*)d_in[21];
    const float* lin0 = (const float*)d_in[22];
    const float* lin1 = (const float*)d_in[23];

    int N = in_sizes[0] / 3;
    int E = in_sizes[3] / 2;
    const int* srcI = eidx;
    const int* dstI = eidx + E;

    float* ws = (float*)d_ws;
    size_t o = 0;
    float* h0     = ws + o; o += (size_t)N * 16;
    float* h1     = ws + o; o += (size_t)N * 12;
    float* eat    = ws + o; o += (size_t)E * 16;
    float* y1s    = ws + o; o += (size_t)E * 3;
    float* oo0    = ws + o; o += (size_t)E * 16;
    float* oo1    = ws + o; o += (size_t)E * 12;
    float* invcnt = ws + o; o += (size_t)N;
    int* cntI   = (int*)(ws + o); o += (size_t)N;
    int* startA = (int*)(ws + o); o += (size_t)N;
    int* cursor = (int*)(ws + o); o += (size_t)N;
    int* srcS   = (int*)(ws + o); o += (size_t)E;
    int* dstS   = (int*)(ws + o); o += (size_t)E;
    unsigned short* w2p = (unsigned short*)(ws + o); o += 2 * 26 * 2 * 64 * 8 / 2;
    unsigned short* w1p = (unsigned short*)(ws + o); o += 2 * 4 * 2 * 64 * 8 / 2;

    hipMemsetAsync(h1,   0, sizeof(float) * (size_t)N * 12, stream);
    hipMemsetAsync(cntI, 0, sizeof(int) * (size_t)N, stream);

    int nblkA = (N + 255) / 256;
    int nblkB = (E + 255) / 256;
    embed_hist_pack_kernel<<<nblkA + nblkB + 30, 256, 0, stream>>>(
        nf, encW, encb, neW1, neb1, neW2, neb2, h0, N, srcI, cntI, E,
        fc2W, fc1W, w2p, w1p, nblkA, nblkB);

    scan_kernel<<<1, 1024, 0, stream>>>(cntI, startA, cursor, invcnt, N);

    edge_pre_kernel<<<nblkB, 256, 0, stream>>>(
        pos, eain, srcI, dstI, cursor, eeW1, eeb1, eeW2, eeb2,
        reW1, reb1, reW2, reb2, eat, y1s, srcS, dstS, E);

    dim3 nub(8, 32);
    int nublk = (N + 31) / 32;
    for (int i = 0; i < 2; ++i) {
        const float* fb1 = fc1b + (size_t)i * 64;
        const float* fb2 = fc2b + (size_t)i * 416;
        const unsigned short* w1pi = w1p + (size_t)i * 4 * 2 * 64 * 8;
        const unsigned short* w2pi = w2p + (size_t)i * 26 * 2 * 64 * 8;
        if (i == 0) {
            fused_tp_kernel<false><<<E / 128, 256, 0, stream>>>(
                h0, h1, eat, y1s, srcS, dstS, w1pi, fb1, w2pi, fb2, oo0, oo1, E);
            node_update_kernel<false><<<nublk, nub, 0, stream>>>(
                h0, h1, oo0, oo1, startA, cntI, invcnt, lin0, lin1, (float*)d_out, N);
        } else {
            fused_tp_kernel<true><<<E / 128, 256, 0, stream>>>(
                h0, h1, eat, y1s, srcS, dstS, w1pi, fb1, w2pi, fb2, oo0, oo1, E);
            node_update_kernel<true><<<nublk, nub, 0, stream>>>(
                h0, h1, oo0, oo1, startA, cntI, invcnt, lin0, lin1, (float*)d_out, N);
        }
    }
}